// Round 11
// baseline (62.614 us; speedup 1.0000x reference)
//
#include <hip/hip_runtime.h>
#include <math.h>

// Problem geometry
#define MTOT  16384      // B*L
#define DM    1024
#define HIDN  128
#define HNB   256
#define NBAT  4
#define CLK   32         // rows per k_mega block == scan chunk
#define NBLK  512        // MTOT/CLK  -> 2 blocks/CU
#define CPB   128        // chunks per batch (4096/32)

typedef _Float16 v8h __attribute__((ext_vector_type(8)));
typedef float    v4f __attribute__((ext_vector_type(4)));
#define MFMA16(a,b,c) __builtin_amdgcn_mfma_f32_16x16x32_f16((a),(b),(c),0,0,0)

// FRAGMENT-ORDERED weight blobs (d_ws when big enough, else out1 region):
//  W1: 32 k-tiles x 16384 B. Tile: h-frags [np 0..3][fi 0..1][64 lanes x 16B]
//      (8 KB) then l-frags at +8192. Frag entry lane l: col=32np+16fi+(l&15),
//      k = kt*32 + (l>>4)*8 + e  (e=0..7, 2B each).
//  W2 @524288: 4 k-tiles x 32768 B. Tile: h [cg 0..15][64 x 16B] (16 KB),
//      l at +16384. Entry lane l: col=cg*16+(l&15), k = ks*32 + (l>>4)*8 + e.
#define W1TILE  16384
#define W2BASE  524288
#define W2TILE  32768
#define BLOB_BYTES 655360

// k_mega LDS map (65536 B -> 2 blocks/CU):
//  GEMM1: raw A fp32 ring 4 x 4096 @0   ([mh][half][64 lanes x 16B] per slot)
//         W1 tri-buffer 3 x 16384 @16384
//  H (post-GEMM1): Hh [mh][ks][64x16B] 8KB @0 | Hl 8KB @8192  (raw dead)
//  Z (post-GEMM2): [32][260] f32 @16384 (33280)               (W1 dead)
#define RAWOFF 0
#define W1OFF  16384
#define HHOFF  0
#define HLOFF  8192
#define ZOFF   16384
#define SMEMSZ 65536

#define VMCNT_(N) asm volatile("s_waitcnt vmcnt(" #N ")" ::: "memory")
#define VMCNT(N) VMCNT_(N)
#define BARRIER() do { asm volatile("s_waitcnt lgkmcnt(0)" ::: "memory"); \
                       __builtin_amdgcn_s_barrier(); } while (0)

typedef const __attribute__((address_space(1))) void* gas1_t;
typedef __attribute__((address_space(3))) void* las3_t;

__device__ __forceinline__ void gld16(const void* g, void* l) {
    __builtin_amdgcn_global_load_lds((gas1_t)g, (las3_t)l, 16, 0, 0);
}

// ---------------------------------------------------------------------------
// K0: weights -> fp16-split fragment-ordered blobs.
//     Xh = fp16(x); Xl = fp16((x - Xh) * 4096)
// ---------------------------------------------------------------------------
__global__ __launch_bounds__(256) void k_prep(
    const float* __restrict__ W1,   // [1024][128]
    const float* __restrict__ W2,   // [128][256]
    char* __restrict__ blobs)
{
    __shared__ float lds[32][260];
    const int t = threadIdx.x, blk = blockIdx.x;
    if (blk < 32) {
        const int k0 = blk * 32;
        #pragma unroll
        for (int i = 0; i < 4; ++i) {
            int j = t + i * 256;
            int k = j >> 5, n4 = (j & 31) << 2;
            *(float4*)&lds[k][n4] = *(const float4*)&W1[(size_t)(k0 + k) * HIDN + n4];
        }
        __syncthreads();
        const int fl = t & 63, np = t >> 6;
        const int kb = (fl >> 4) * 8;
        #pragma unroll
        for (int fi = 0; fi < 2; ++fi) {
            const int col = 32 * np + 16 * fi + (fl & 15);
            union { _Float16 h[8]; int4 v; } H, L;
            #pragma unroll
            for (int e = 0; e < 8; ++e) {
                float v = lds[kb + e][col];
                _Float16 hh = (_Float16)v;
                H.h[e] = hh;
                L.h[e] = (_Float16)((v - (float)hh) * 4096.f);
            }
            char* d = blobs + blk * W1TILE + np * 2048 + fi * 1024 + fl * 16;
            *(int4*)d = H.v;
            *(int4*)(d + 8192) = L.v;
        }
    } else {
        const int ks = blk - 32, k0 = ks * 32;
        #pragma unroll
        for (int i = 0; i < 8; ++i) {
            int j = t + i * 256;
            int k = j >> 6, n4 = (j & 63) << 2;
            *(float4*)&lds[k][n4] = *(const float4*)&W2[(size_t)(k0 + k) * HNB + n4];
        }
        __syncthreads();
        const int fl = t & 63, cg0 = t >> 6;
        const int kb = (fl >> 4) * 8;
        #pragma unroll
        for (int i = 0; i < 4; ++i) {
            const int cg = cg0 * 4 + i;
            const int col = cg * 16 + (fl & 15);
            union { _Float16 h[8]; int4 v; } H, L;
            #pragma unroll
            for (int e = 0; e < 8; ++e) {
                float v = lds[kb + e][col];
                _Float16 hh = (_Float16)v;
                H.h[e] = hh;
                L.h[e] = (_Float16)((v - (float)hh) * 4096.f);
            }
            char* d = blobs + W2BASE + ks * W2TILE + cg * 1024 + fl * 16;
            *(int4*)d = H.v;
            *(int4*)(d + 16384) = L.v;
        }
    }
}

// ---------------------------------------------------------------------------
// K1: mega. Block = 32 rows = one chunk; 512 thr (8 waves = 2mh x 4np),
// grid 512 -> 2 blocks/CU, 4 waves/SIMD. All LDS frag reads lane-linear
// (conflict-free). A: glds raw fp32 4-slot ring (dist-3, frag-ordered via
// pre-arranged source), consumer-side in-register split. W1: glds byte-copy
// tri-buffer (dist-2). Counted vmcnt; lgkm-only barriers. Full K per wave.
// ---------------------------------------------------------------------------
__global__ __launch_bounds__(512, 4) void k_mega(
    const float* __restrict__ A,      // content [16384][1024]
    const float* __restrict__ theta,  // [16384][256]
    const float* __restrict__ b1, const float* __restrict__ b2,
    const float* __restrict__ logPi, const float* __restrict__ logR,
    const char* __restrict__ blobs,
    float* __restrict__ out0, float* __restrict__ out2,
    float* fill1, float* fill3,       // non-null only in ws mode
    float* carry, int cstride)
{
    __shared__ __attribute__((aligned(16))) char smem[SMEMSZ];

    const int tid  = threadIdx.x;
    const int blk  = blockIdx.x;
    const int m0   = blk * CLK;
    const int lane = tid & 63;
    const int wid  = tid >> 6;
    const int ln15 = lane & 15;
    const int q    = lane >> 4;
    const int np   = wid & 3;    // col group
    const int mh   = wid >> 2;   // row half

    // ---- raw A staging (waves 0-3; wave w = region [mh_s][half_s], 1 glds/step)
    //      LDS slot layout [mh][half][lane*16]: entry lane l holds
    //      A[16mh+(l&15)][kt*32 + (l>>4)*8 + half*4 .. +3]
    const int mh_s = wid >> 1, half_s = wid & 1;
    const float* aSrc = A + (size_t)(m0 + 16 * mh_s + ln15) * DM + q * 8 + half_s * 4;
    const int rawDst = wid * 1024 + lane * 16;

    // ---- W1 staging (waves 4-7; wave 4+wq byte-copies np-region wq: 4 glds/step)
    const int wq = wid & 3;
    const char* wSrc = blobs + wq * 2048 + (size_t)lane * 16;
    const int   wDst = wq * 2048 + lane * 16;

    v4f acc1[2], acc2[2];
    acc1[0] = acc1[1] = (v4f){0.f, 0.f, 0.f, 0.f};
    acc2[0] = acc2[1] = (v4f){0.f, 0.f, 0.f, 0.f};

#define STEP(KT, AV, WV, DO_RAW, DO_W) do { \
    if (wid < 4) { \
        if (DO_RAW) gld16(aSrc + (size_t)((KT) + 3) * 32, \
                          smem + RAWOFF + (((KT) + 3) & 3) * 4096 + rawDst); \
    } else if (DO_W) { \
        const char* ws_ = wSrc + (size_t)((KT) + 2) * W1TILE; \
        char* wd_ = smem + W1OFF + (((KT) + 2) % 3) * 16384 + wDst; \
        gld16(ws_, wd_);             gld16(ws_ + 1024, wd_ + 1024); \
        gld16(ws_ + 8192, wd_ + 8192); gld16(ws_ + 9216, wd_ + 9216); \
    } \
    { \
        const char* rawb = smem + RAWOFF + ((KT) & 3) * 4096 + mh * 2048 + lane * 16; \
        v4f lo = *(const v4f*)rawb; \
        v4f hi = *(const v4f*)(rawb + 1024); \
        const char* wbB = smem + W1OFF + ((KT) % 3) * 16384 + np * 2048 + lane * 16; \
        v8h wh0 = *(const v8h*)(wbB); \
        v8h wh1 = *(const v8h*)(wbB + 1024); \
        v8h wl0 = *(const v8h*)(wbB + 8192); \
        v8h wl1 = *(const v8h*)(wbB + 9216); \
        v8h ah, al; \
        _Pragma("unroll") \
        for (int e_ = 0; e_ < 4; ++e_) { \
            _Float16 t0_ = (_Float16)lo[e_]; \
            ah[e_] = t0_; \
            al[e_] = (_Float16)((lo[e_] - (float)t0_) * 4096.f); \
            _Float16 t1_ = (_Float16)hi[e_]; \
            ah[e_ + 4] = t1_; \
            al[e_ + 4] = (_Float16)((hi[e_] - (float)t1_) * 4096.f); \
        } \
        acc1[0] = MFMA16(ah, wh0, acc1[0]); \
        acc2[0] = MFMA16(ah, wl0, acc2[0]); \
        acc2[0] = MFMA16(al, wh0, acc2[0]); \
        acc1[1] = MFMA16(ah, wh1, acc1[1]); \
        acc2[1] = MFMA16(ah, wl1, acc2[1]); \
        acc2[1] = MFMA16(al, wh1, acc2[1]); \
    } \
    if (wid < 4) { VMCNT(AV); } else { VMCNT(WV); } \
    BARRIER(); \
} while (0)

    // ---- prologue: raw 0,1,2 -> slots 0,1,2; W 0,1 -> bufs 0,1
    if (wid < 4) {
        gld16(aSrc,      smem + RAWOFF + 0 * 4096 + rawDst);
        gld16(aSrc + 32, smem + RAWOFF + 1 * 4096 + rawDst);
        gld16(aSrc + 64, smem + RAWOFF + 2 * 4096 + rawDst);
        VMCNT(2);
    } else {
        #pragma unroll
        for (int t2 = 0; t2 < 2; ++t2) {
            const char* ws_ = wSrc + (size_t)t2 * W1TILE;
            char* wd_ = smem + W1OFF + t2 * 16384 + wDst;
            gld16(ws_, wd_);               gld16(ws_ + 1024, wd_ + 1024);
            gld16(ws_ + 8192, wd_ + 8192); gld16(ws_ + 9216, wd_ + 9216);
        }
        VMCNT(4);
    }
    BARRIER();

    // ---- GEMM1: 32 k-steps
    STEP(0,2,4,1,1);  STEP(1,2,4,1,1);  STEP(2,2,4,1,1);  STEP(3,2,4,1,1);
    STEP(4,2,4,1,1);  STEP(5,2,4,1,1);  STEP(6,2,4,1,1);  STEP(7,2,4,1,1);
    STEP(8,2,4,1,1);  STEP(9,2,4,1,1);  STEP(10,2,4,1,1); STEP(11,2,4,1,1);
    STEP(12,2,4,1,1); STEP(13,2,4,1,1); STEP(14,2,4,1,1); STEP(15,2,4,1,1);
    STEP(16,2,4,1,1); STEP(17,2,4,1,1); STEP(18,2,4,1,1); STEP(19,2,4,1,1);
    STEP(20,2,4,1,1); STEP(21,2,4,1,1); STEP(22,2,4,1,1); STEP(23,2,4,1,1);
    STEP(24,2,4,1,1); STEP(25,2,4,1,1); STEP(26,2,4,1,1); STEP(27,2,4,1,1);
    STEP(28,2,4,1,1); STEP(29,1,4,0,1); STEP(30,0,0,0,0); STEP(31,0,0,0,0);

    // ---- GELU -> H split, fragment-ordered (raw region dead)
    const float inv = 1.f / 4096.f;
    #pragma unroll
    for (int ni = 0; ni < 2; ++ni) {
        const int colH = 32 * np + 16 * ni + ln15;
        const float bv = b1[colH];
        const int qH = (colH >> 3) & 3;
        const int eH = colH & 7;
        #pragma unroll
        for (int r = 0; r < 4; ++r) {
            float y = acc1[ni][r] + acc2[ni][r] * inv + bv;
            float h = 0.5f * y * (1.f + erff(y * 0.70710678118654752f));
            _Float16 hh = (_Float16)h;
            _Float16 hl = (_Float16)((h - (float)hh) * 4096.f);
            const int fl = (4 * q + r) + 16 * qH;
            const int byte_ = mh * 4096 + np * 1024 + fl * 16 + eH * 2;
            *(_Float16*)(smem + HHOFF + byte_) = hh;
            *(_Float16*)(smem + HLOFF + byte_) = hl;
        }
    }
    BARRIER();

    // ---- GEMM2: out 32x256; wave (mh, np) -> rows 16mh..+15, cols 64np..+63
    //      H-frag reads lane-linear; W2 register-direct from L2 blob.
    v4f c1[4], c2[4];
    #pragma unroll
    for (int i = 0; i < 4; ++i) {
        c1[i] = (v4f){0.f, 0.f, 0.f, 0.f};
        c2[i] = (v4f){0.f, 0.f, 0.f, 0.f};
    }
    #pragma unroll
    for (int ks = 0; ks < 4; ++ks) {
        v8h hh = *(const v8h*)(smem + HHOFF + mh * 4096 + ks * 1024 + lane * 16);
        v8h hl = *(const v8h*)(smem + HLOFF + mh * 4096 + ks * 1024 + lane * 16);
        #pragma unroll
        for (int ni = 0; ni < 4; ++ni) {
            const char* wp = blobs + W2BASE + (size_t)ks * W2TILE
                           + (4 * np + ni) * 1024 + (size_t)lane * 16;
            v8h w2h = *(const v8h*)wp;
            v8h w2l = *(const v8h*)(wp + 16384);
            c1[ni] = MFMA16(hh, w2h, c1[ni]);
            c2[ni] = MFMA16(hh, w2l, c2[ni]);
            c2[ni] = MFMA16(hl, w2h, c2[ni]);
        }
    }

    // ---- z = pi*tanh(y2) -> Z LDS (over dead W1 region)
    #pragma unroll
    for (int ni = 0; ni < 4; ++ni) {
        const int col = 64 * np + 16 * ni + ln15;
        const float bv = b2[col];
        #pragma unroll
        for (int r = 0; r < 4; ++r) {
            const int row = 16 * mh + 4 * q + r;
            float y2 = c1[ni][r] + c2[ni][r] * inv + bv;
            *(float*)(smem + ZOFF + row * 1040 + col * 4) =
                3.14159265358979323846f * tanhf(y2);
        }
    }
    BARRIER();

    // ---- scan (waves 0-3) + fills (waves 4-7)
    if (tid < 256) {
        const int c = tid;
        const float Pi = expf(logPi[c]);
        const float Rr = expf(logR[c]);
        const float Kc = Pi / fmaxf(Pi + Rr, 1e-8f);
        const float alpha = 1.f - Kc;
        float d = 0.f;
        float tv[2][16];
        #pragma unroll
        for (int i = 0; i < 16; ++i)
            tv[0][i] = theta[(size_t)(m0 + i) * HNB + c];
        #pragma unroll
        for (int g = 0; g < 2; ++g) {
            if (g < 1) {
                #pragma unroll
                for (int i = 0; i < 16; ++i)
                    tv[1][i] = theta[(size_t)(m0 + 16 + i) * HNB + c];
            }
            float sv[16];
            #pragma unroll
            for (int i = 0; i < 16; ++i) {
                float z = *(const float*)(smem + ZOFF + (g * 16 + i) * 1040 + c * 4);
                float diff = z - tv[g][i];
                float kq = rintf(diff * 0.15915494309189533577f);
                float nu = (float)((double)diff - (double)kq * 6.283185307179586476925286766559);
                d = fmaf(alpha, d, Kc * nu);
                sv[i] = tv[g][i] + d;
            }
            #pragma unroll
            for (int i = 0; i < 16; ++i)
                out0[(size_t)(m0 + g * 16 + i) * HNB + c] = sv[i];
        }
        carry[(size_t)blk * cstride + c] = d;
    } else {
        const int c = tid - 256;
        const float Pi = expf(logPi[c]);
        const float Rr = expf(logR[c]);
        const float Kc = Pi / fmaxf(Pi + Rr, 1e-8f);
        if (fill1) {
            #pragma unroll 4
            for (int i = 0; i < CLK; ++i) {
                size_t idx = (size_t)(m0 + i) * HNB + c;
                out2[idx]  = Kc;
                fill1[idx] = Pi;
                fill3[idx] = Rr;
            }
        } else {
            #pragma unroll 4
            for (int i = 0; i < CLK; ++i)
                out2[(size_t)(m0 + i) * HNB + c] = Kc;
        }
    }
#undef STEP
}

// ---------------------------------------------------------------------------
// K2: exclusive scan of chunk carries (factor alpha^32), one block per batch.
// ---------------------------------------------------------------------------
__global__ __launch_bounds__(256) void k_cscan(
    const float* __restrict__ logPi, const float* __restrict__ logR,
    float* carry, int cstride)
{
    const int c = threadIdx.x, b = blockIdx.x;
    const float Pi = expf(logPi[c]);
    const float Rr = expf(logR[c]);
    const float alpha = 1.f - Pi / fmaxf(Pi + Rr, 1e-8f);
    float A32 = alpha;
    #pragma unroll
    for (int i = 0; i < 5; ++i) A32 *= A32;   // alpha^32
    float D = 0.f;
    for (int s0 = 0; s0 < CPB; s0 += 16) {
        float a[16];
        #pragma unroll
        for (int j = 0; j < 16; ++j)
            a[j] = carry[(size_t)(b * CPB + s0 + j) * cstride + c];
        #pragma unroll
        for (int j = 0; j < 16; ++j) {
            carry[(size_t)(b * CPB + s0 + j) * cstride + c] = D;
            D = fmaf(A32, D, a[j]);
        }
    }
}

// ---------------------------------------------------------------------------
// K3: out0 += alpha^(i+1)*D; in fallback mode also fills Pi/R.
// ---------------------------------------------------------------------------
__global__ __launch_bounds__(256) void k_apply(
    const float* __restrict__ logPi, const float* __restrict__ logR,
    float* __restrict__ out0, float* out1, float* out3,
    const float* carry, int cstride, int do_fills)
{
    const int blk = blockIdx.x;
    const int c = threadIdx.x;
    const float Pi = expf(logPi[c]);
    const float Rr = expf(logR[c]);
    const float Kc = Pi / fmaxf(Pi + Rr, 1e-8f);
    const float alpha = 1.f - Kc;
    float D = carry[(size_t)blk * cstride + c];
    float w = alpha * D;
    const size_t base = (size_t)blk * (CLK * HNB) + c;
    if (do_fills) {
        #pragma unroll 4
        for (int i = 0; i < CLK; ++i) {
            size_t idx = base + (size_t)i * HNB;
            out0[idx] += w;
            out1[idx] = Pi;
            out3[idx] = Rr;
            w *= alpha;
        }
    } else {
        #pragma unroll 4
        for (int i = 0; i < CLK; ++i) {
            size_t idx = base + (size_t)i * HNB;
            out0[idx] += w;
            w *= alpha;
        }
    }
}

extern "C" void kernel_launch(void* const* d_in, const int* in_sizes, int n_in,
                              void* d_out, int out_size, void* d_ws, size_t ws_size,
                              hipStream_t stream) {
    const float* theta   = (const float*)d_in[0];
    const float* content = (const float*)d_in[1];
    const float* W1      = (const float*)d_in[2];
    const float* b1      = (const float*)d_in[3];
    const float* W2      = (const float*)d_in[4];
    const float* b2      = (const float*)d_in[5];
    const float* logPi   = (const float*)d_in[6];
    const float* logR    = (const float*)d_in[7];

    float* out  = (float*)d_out;
    float* out0 = out;
    float* out1 = out + (size_t)MTOT * HNB;
    float* out2 = out + (size_t)2 * MTOT * HNB;
    float* out3 = out + (size_t)3 * MTOT * HNB;

    const size_t carry_bytes = (size_t)NBLK * 256 * 4;          // 512 KB
    const size_t need = carry_bytes + BLOB_BYTES;               // ~1.13 MB
    float* carry; int cstride, do_fills; char* blobs;
    float *f1, *f3;
    if (ws_size >= need) {
        carry   = (float*)d_ws;
        cstride = 256;
        blobs   = (char*)d_ws + carry_bytes;
        f1 = out1; f3 = out3; do_fills = 0;
    } else {
        carry   = out3;                 // chunk's own out3 rows (blk*8192)
        cstride = CLK * HNB;            // 8192
        blobs   = (char*)out1;          // blobs live in out1 until k_apply fills
        f1 = nullptr; f3 = nullptr; do_fills = 1;
    }

    hipLaunchKernelGGL(k_prep, dim3(36), dim3(256), 0, stream, W1, W2, blobs);
    hipLaunchKernelGGL(k_mega, dim3(NBLK), dim3(512), 0, stream,
                       content, theta, b1, b2, logPi, logR, blobs,
                       out0, out2, f1, f3, carry, cstride);
    hipLaunchKernelGGL(k_cscan, dim3(NBAT), dim3(256), 0, stream,
                       logPi, logR, carry, cstride);
    hipLaunchKernelGGL(k_apply, dim3(NBLK), dim3(256), 0, stream,
                       logPi, logR, out0, out1, out3, carry, cstride, do_fills);
}

// Round 12
// 61.335 us; speedup vs baseline: 1.0209x; 1.0209x over previous
//
#include <hip/hip_runtime.h>
#include <math.h>

// Problem geometry
#define MTOT  16384      // B*L
#define DM    1024
#define HIDN  128
#define HNB   256
#define NBAT  4
#define CLK   64         // rows per k_mega block == scan chunk
#define NBLK  256        // MTOT/CLK
#define CPB   64         // chunks per batch (4096/64)

typedef _Float16 v8h  __attribute__((ext_vector_type(8)));
typedef float    v4f  __attribute__((ext_vector_type(4)));
typedef float    v16f __attribute__((ext_vector_type(16)));
#define MFMA32(a,b,c) __builtin_amdgcn_mfma_f32_32x32x16_f16((a),(b),(c),0,0,0)

// FRAGMENT-ORDERED blobs for 32x32x16 (d_ws when big enough, else out1):
//  W1: 32 k-tiles x 16384 B. Tile: h-frags [np*2+kb][64 lanes x16B] (8KB), l @+8192.
//      Entry lane l, frag(np,kb): W1[kt*32+kb*16+(l>>5)*8+e][32np+(l&31)], e=0..7.
//  W2 @524288: 4 ks-tiles x 32768 B: h [cg*2+kb][64x16B] (16KB), l @+16384.
#define W1TILE 16384
#define W2BASE 524288
#define W2TILE 32768
#define BLOB_BYTES 655360

// k_mega LDS map (115712 B):
//  GEMM1: raw A fp32 ring 6 x 8192 @0  (piece w: rh=w>>2,kb=(w>>1)&1,half=w&1)
//         W1 pair-dbuf 2 x 32768 @49152
//  H (post-GEMM1): Hh [rh*8+kb2][64x16B] 16KB @0 | Hl @16384 (A-ring dead)
//  Z (post-GEMM2): [64][260] f32 @49152 (66560)              (W1 dead)
#define RAWOFF 0
#define W1OFF  49152
#define HHOFF  0
#define HLOFF  16384
#define ZOFF   49152
#define SMEMSZ 115712

#define VMCNT_(N) asm volatile("s_waitcnt vmcnt(" #N ")" ::: "memory")
#define VMCNT(N) VMCNT_(N)
#define BARRIER() do { asm volatile("s_waitcnt lgkmcnt(0)" ::: "memory"); \
                       __builtin_amdgcn_s_barrier(); } while (0)

typedef const __attribute__((address_space(1))) void* gas1_t;
typedef __attribute__((address_space(3))) void* las3_t;

__device__ __forceinline__ void gld16(const void* g, void* l) {
    __builtin_amdgcn_global_load_lds((gas1_t)g, (las3_t)l, 16, 0, 0);
}

// ---------------------------------------------------------------------------
// K0: weights -> fp16-split fragment-ordered blobs (32x32 shape).
//     Xh = fp16(x); Xl = fp16((x - Xh) * 4096)
// ---------------------------------------------------------------------------
__global__ __launch_bounds__(256) void k_prep(
    const float* __restrict__ W1,   // [1024][128]
    const float* __restrict__ W2,   // [128][256]
    char* __restrict__ blobs)
{
    __shared__ float lds[32][260];
    const int t = threadIdx.x, blk = blockIdx.x;
    if (blk < 32) {
        const int k0 = blk * 32;
        #pragma unroll
        for (int i = 0; i < 4; ++i) {
            int j = t + i * 256;
            int k = j >> 5, n4 = (j & 31) << 2;
            *(float4*)&lds[k][n4] = *(const float4*)&W1[(size_t)(k0 + k) * HIDN + n4];
        }
        __syncthreads();
        const int l = t & 63, fi = t >> 6;      // fi = np
        #pragma unroll
        for (int kb = 0; kb < 2; ++kb) {
            union { _Float16 h[8]; int4 v; } H, L;
            #pragma unroll
            for (int e = 0; e < 8; ++e) {
                float v = lds[kb * 16 + (l >> 5) * 8 + e][32 * fi + (l & 31)];
                _Float16 hh = (_Float16)v;
                H.h[e] = hh;
                L.h[e] = (_Float16)((v - (float)hh) * 4096.f);
            }
            char* d = blobs + blk * W1TILE + (fi * 2 + kb) * 1024 + l * 16;
            *(int4*)d = H.v;
            *(int4*)(d + 8192) = L.v;
        }
    } else {
        const int ks = blk - 32, k0 = ks * 32;
        #pragma unroll
        for (int i = 0; i < 8; ++i) {
            int j = t + i * 256;
            int k = j >> 6, n4 = (j & 63) << 2;
            *(float4*)&lds[k][n4] = *(const float4*)&W2[(size_t)(k0 + k) * HNB + n4];
        }
        __syncthreads();
        const int l = t & 63, fi = t >> 6;
        #pragma unroll
        for (int jj = 0; jj < 2; ++jj) {
            const int cg = fi * 2 + jj;
            #pragma unroll
            for (int kb = 0; kb < 2; ++kb) {
                union { _Float16 h[8]; int4 v; } H, L;
                #pragma unroll
                for (int e = 0; e < 8; ++e) {
                    float v = lds[kb * 16 + (l >> 5) * 8 + e][32 * cg + (l & 31)];
                    _Float16 hh = (_Float16)v;
                    H.h[e] = hh;
                    L.h[e] = (_Float16)((v - (float)hh) * 4096.f);
                }
                char* d = blobs + W2BASE + ks * W2TILE + (cg * 2 + kb) * 1024 + l * 16;
                *(int4*)d = H.v;
                *(int4*)(d + 16384) = L.v;
            }
        }
    }
}

// ---------------------------------------------------------------------------
// K1: mega. Block = 64 rows = one chunk; 512 thr (8 waves), grid 256.
// GEMM1: wave tile 32x32 via mfma_32x32x16 (rh=wid>>2, np=wid&3); 16 BK64
// phases; A raw 6-slot ring (dist-2 phases), W1 pair-dbuf (dist-1); uniform
// staging roles; counted VMCNT(2) per phase. Consumer-side in-register split.
// GELU -> H frag-ordered LDS -> GEMM2 32x32 (W2 L2-direct) -> z -> scan.
// ---------------------------------------------------------------------------
__global__ __launch_bounds__(512, 2) void k_mega(
    const float* __restrict__ A,      // content [16384][1024]
    const float* __restrict__ theta,  // [16384][256]
    const float* __restrict__ b1, const float* __restrict__ b2,
    const float* __restrict__ logPi, const float* __restrict__ logR,
    const char* __restrict__ blobs,
    float* __restrict__ out0, float* __restrict__ out2,
    float* fill1, float* fill3,       // non-null only in ws mode
    float* carry, int cstride)
{
    __shared__ __attribute__((aligned(16))) char smem[SMEMSZ];

    const int tid  = threadIdx.x;
    const int blk  = blockIdx.x;
    const int m0   = blk * CLK;
    const int lane = tid & 63;
    const int wid  = tid >> 6;
    const int c5   = lane & 31;
    const int g    = lane >> 5;
    const int np   = wid & 3;    // col group (32*np..+31)
    const int rh   = wid >> 2;   // row half (32*rh..+31)

    // ---- A staging: piece w = rh_s*4 + kb_s*2 + half_s; 1 glds per tile
    const int rh_s = wid >> 2, kb_s = (wid >> 1) & 1, half_s = wid & 1;
    const float* aSrc = A + (size_t)(m0 + 32 * rh_s + c5) * DM
                      + kb_s * 16 + g * 8 + half_s * 4;
    const int rawPiece = wid * 1024 + lane * 16;

    // ---- W1 staging: wave copies bytes [wid*4096,+4096) of each 32KB pair
    const char* wSrc = blobs + (size_t)wid * 4096 + (size_t)lane * 16;
    const int   wDst = W1OFF + wid * 4096 + lane * 16;

    v16f acc1, acc2;
    #pragma unroll
    for (int i = 0; i < 16; ++i) { acc1[i] = 0.f; acc2[i] = 0.f; }

    // ---- prologue: A tiles 0,1 ; W pair(0,1)->buf0 ; A tiles 2,3
    gld16(aSrc,      smem + RAWOFF + 0 * 8192 + rawPiece);
    gld16(aSrc + 32, smem + RAWOFF + 1 * 8192 + rawPiece);
    #pragma unroll
    for (int i = 0; i < 4; ++i)
        gld16(wSrc + i * 1024, smem + wDst + i * 1024);
    gld16(aSrc + 64, smem + RAWOFF + 2 * 8192 + rawPiece);
    gld16(aSrc + 96, smem + RAWOFF + 3 * 8192 + rawPiece);
    VMCNT(2);
    BARRIER();

#define PHASE(P) do { \
    if ((P) <= 14) { \
        const char* ws_ = wSrc + (size_t)(2 * (P) + 2) * W1TILE; \
        char* wd_ = smem + (((P) + 1) & 1) * 32768 + wDst; \
        gld16(ws_, wd_);               gld16(ws_ + 1024, wd_ + 1024); \
        gld16(ws_ + 2048, wd_ + 2048); gld16(ws_ + 3072, wd_ + 3072); \
    } \
    if ((P) <= 13) { \
        gld16(aSrc + (size_t)(2 * (P) + 4) * 32, \
              smem + RAWOFF + ((2 * (P) + 4) % 6) * 8192 + rawPiece); \
        gld16(aSrc + (size_t)(2 * (P) + 5) * 32, \
              smem + RAWOFF + ((2 * (P) + 5) % 6) * 8192 + rawPiece); \
    } \
    _Pragma("unroll") \
    for (int t_ = 0; t_ < 2; ++t_) { \
        const char* slot_ = smem + RAWOFF + ((2 * (P) + t_) % 6) * 8192; \
        const char* wb_ = smem + W1OFF + ((P) & 1) * 32768 + t_ * 16384; \
        _Pragma("unroll") \
        for (int kb_ = 0; kb_ < 2; ++kb_) { \
            v4f lo_ = *(const v4f*)(slot_ + (rh * 4 + kb_ * 2) * 1024 + lane * 16); \
            v4f hi_ = *(const v4f*)(slot_ + (rh * 4 + kb_ * 2 + 1) * 1024 + lane * 16); \
            v8h ah_, al_; \
            _Pragma("unroll") \
            for (int e_ = 0; e_ < 4; ++e_) { \
                _Float16 t0_ = (_Float16)lo_[e_]; \
                ah_[e_] = t0_; \
                al_[e_] = (_Float16)((lo_[e_] - (float)t0_) * 4096.f); \
                _Float16 t1_ = (_Float16)hi_[e_]; \
                ah_[e_ + 4] = t1_; \
                al_[e_ + 4] = (_Float16)((hi_[e_] - (float)t1_) * 4096.f); \
            } \
            v8h wh_ = *(const v8h*)(wb_ + (np * 2 + kb_) * 1024 + lane * 16); \
            v8h wl_ = *(const v8h*)(wb_ + 8192 + (np * 2 + kb_) * 1024 + lane * 16); \
            acc1 = MFMA32(ah_, wh_, acc1); \
            acc2 = MFMA32(ah_, wl_, acc2); \
            acc2 = MFMA32(al_, wh_, acc2); \
        } \
    } \
    if ((P) <= 13)      { VMCNT(2); } \
    else if ((P) == 14) { VMCNT(0); } \
    BARRIER(); \
} while (0)

    PHASE(0);  PHASE(1);  PHASE(2);  PHASE(3);
    PHASE(4);  PHASE(5);  PHASE(6);  PHASE(7);
    PHASE(8);  PHASE(9);  PHASE(10); PHASE(11);
    PHASE(12); PHASE(13); PHASE(14); PHASE(15);
#undef PHASE

    // ---- GELU -> H split, fragment-ordered (A-ring dead)
    const float inv = 1.f / 4096.f;
    {
        const int col = 32 * np + c5;
        const float bv = b1[col];
        const int kb2 = col >> 4;
        const int fragBase = (rh * 8 + kb2) * 1024 + ((col & 15) >> 3) * 512
                           + (col & 7) * 2;
        #pragma unroll
        for (int reg = 0; reg < 16; ++reg) {
            const int row32 = (reg & 3) + 8 * (reg >> 2) + 4 * g;
            float y = acc1[reg] + acc2[reg] * inv + bv;
            float h = 0.5f * y * (1.f + erff(y * 0.70710678118654752f));
            _Float16 hh = (_Float16)h;
            _Float16 hl = (_Float16)((h - (float)hh) * 4096.f);
            *(_Float16*)(smem + HHOFF + fragBase + row32 * 16) = hh;
            *(_Float16*)(smem + HLOFF + fragBase + row32 * 16) = hl;
        }
    }
    BARRIER();

    // ---- GEMM2: out 64x256; wave (rh, cg ∈ {np, np+4}); K=128 (8 kb2)
    v16f d1[2], d2[2];
    #pragma unroll
    for (int i = 0; i < 16; ++i) {
        d1[0][i] = 0.f; d1[1][i] = 0.f; d2[0][i] = 0.f; d2[1][i] = 0.f;
    }
    #pragma unroll
    for (int kb2 = 0; kb2 < 8; ++kb2) {
        v8h hh = *(const v8h*)(smem + HHOFF + (rh * 8 + kb2) * 1024 + lane * 16);
        v8h hl = *(const v8h*)(smem + HLOFF + (rh * 8 + kb2) * 1024 + lane * 16);
        const int ks = kb2 >> 1, kbl = kb2 & 1;
        #pragma unroll
        for (int ti = 0; ti < 2; ++ti) {
            const int cg = np + ti * 4;
            const char* wp = blobs + W2BASE + (size_t)ks * W2TILE
                           + (cg * 2 + kbl) * 1024 + (size_t)lane * 16;
            v8h w2h = *(const v8h*)wp;
            v8h w2l = *(const v8h*)(wp + 16384);
            d1[ti] = MFMA32(hh, w2h, d1[ti]);
            d2[ti] = MFMA32(hh, w2l, d2[ti]);
            d2[ti] = MFMA32(hl, w2h, d2[ti]);
        }
    }

    // ---- z = pi*tanh(y2) -> Z LDS (W1 region dead)
    #pragma unroll
    for (int ti = 0; ti < 2; ++ti) {
        const int col = 32 * (np + ti * 4) + c5;
        const float bv = b2[col];
        #pragma unroll
        for (int reg = 0; reg < 16; ++reg) {
            const int row = 32 * rh + (reg & 3) + 8 * (reg >> 2) + 4 * g;
            float y2 = d1[ti][reg] + d2[ti][reg] * inv + bv;
            *(float*)(smem + ZOFF + row * 1040 + col * 4) =
                3.14159265358979323846f * tanhf(y2);
        }
    }
    BARRIER();

    // ---- scan (waves 0-3) + fills (waves 4-7)
    if (tid < 256) {
        const int c = tid;
        const float Pi = expf(logPi[c]);
        const float Rr = expf(logR[c]);
        const float Kc = Pi / fmaxf(Pi + Rr, 1e-8f);
        const float alpha = 1.f - Kc;
        float d = 0.f;
        float tv[2][16];
        #pragma unroll
        for (int i = 0; i < 16; ++i)
            tv[0][i] = theta[(size_t)(m0 + i) * HNB + c];
        #pragma unroll
        for (int gr = 0; gr < 4; ++gr) {
            const int cur = gr & 1;
            if (gr < 3) {
                #pragma unroll
                for (int i = 0; i < 16; ++i)
                    tv[cur ^ 1][i] = theta[(size_t)(m0 + (gr + 1) * 16 + i) * HNB + c];
            }
            float sv[16];
            #pragma unroll
            for (int i = 0; i < 16; ++i) {
                float z = *(const float*)(smem + ZOFF + (gr * 16 + i) * 1040 + c * 4);
                float diff = z - tv[cur][i];
                float kq = rintf(diff * 0.15915494309189533577f);
                float nu = (float)((double)diff - (double)kq * 6.283185307179586476925286766559);
                d = fmaf(alpha, d, Kc * nu);
                sv[i] = tv[cur][i] + d;
            }
            #pragma unroll
            for (int i = 0; i < 16; ++i)
                out0[(size_t)(m0 + gr * 16 + i) * HNB + c] = sv[i];
        }
        carry[(size_t)blk * cstride + c] = d;
    } else {
        const int c = tid - 256;
        const float Pi = expf(logPi[c]);
        const float Rr = expf(logR[c]);
        const float Kc = Pi / fmaxf(Pi + Rr, 1e-8f);
        if (fill1) {
            #pragma unroll 4
            for (int i = 0; i < CLK; ++i) {
                size_t idx = (size_t)(m0 + i) * HNB + c;
                out2[idx]  = Kc;
                fill1[idx] = Pi;
                fill3[idx] = Rr;
            }
        } else {
            #pragma unroll 4
            for (int i = 0; i < CLK; ++i)
                out2[(size_t)(m0 + i) * HNB + c] = Kc;
        }
    }
}

// ---------------------------------------------------------------------------
// K2: exclusive scan of chunk carries (factor alpha^64), one block per batch.
// ---------------------------------------------------------------------------
__global__ __launch_bounds__(256) void k_cscan(
    const float* __restrict__ logPi, const float* __restrict__ logR,
    float* carry, int cstride)
{
    const int c = threadIdx.x, b = blockIdx.x;
    const float Pi = expf(logPi[c]);
    const float Rr = expf(logR[c]);
    const float alpha = 1.f - Pi / fmaxf(Pi + Rr, 1e-8f);
    float A64 = alpha;
    #pragma unroll
    for (int i = 0; i < 6; ++i) A64 *= A64;   // alpha^64
    float D = 0.f;
    for (int s0 = 0; s0 < CPB; s0 += 16) {
        float a[16];
        #pragma unroll
        for (int j = 0; j < 16; ++j)
            a[j] = carry[(size_t)(b * CPB + s0 + j) * cstride + c];
        #pragma unroll
        for (int j = 0; j < 16; ++j) {
            carry[(size_t)(b * CPB + s0 + j) * cstride + c] = D;
            D = fmaf(A64, D, a[j]);
        }
    }
}

// ---------------------------------------------------------------------------
// K3: out0 += alpha^(i+1)*D; in fallback mode also fills Pi/R.
// ---------------------------------------------------------------------------
__global__ __launch_bounds__(256) void k_apply(
    const float* __restrict__ logPi, const float* __restrict__ logR,
    float* __restrict__ out0, float* out1, float* out3,
    const float* carry, int cstride, int do_fills)
{
    const int blk = blockIdx.x;
    const int c = threadIdx.x;
    const float Pi = expf(logPi[c]);
    const float Rr = expf(logR[c]);
    const float Kc = Pi / fmaxf(Pi + Rr, 1e-8f);
    const float alpha = 1.f - Kc;
    float D = carry[(size_t)blk * cstride + c];
    float w = alpha * D;
    const size_t base = (size_t)blk * (CLK * HNB) + c;
    if (do_fills) {
        #pragma unroll 4
        for (int i = 0; i < CLK; ++i) {
            size_t idx = base + (size_t)i * HNB;
            out0[idx] += w;
            out1[idx] = Pi;
            out3[idx] = Rr;
            w *= alpha;
        }
    } else {
        #pragma unroll 4
        for (int i = 0; i < CLK; ++i) {
            size_t idx = base + (size_t)i * HNB;
            out0[idx] += w;
            w *= alpha;
        }
    }
}

extern "C" void kernel_launch(void* const* d_in, const int* in_sizes, int n_in,
                              void* d_out, int out_size, void* d_ws, size_t ws_size,
                              hipStream_t stream) {
    const float* theta   = (const float*)d_in[0];
    const float* content = (const float*)d_in[1];
    const float* W1      = (const float*)d_in[2];
    const float* b1      = (const float*)d_in[3];
    const float* W2      = (const float*)d_in[4];
    const float* b2      = (const float*)d_in[5];
    const float* logPi   = (const float*)d_in[6];
    const float* logR    = (const float*)d_in[7];

    float* out  = (float*)d_out;
    float* out0 = out;
    float* out1 = out + (size_t)MTOT * HNB;
    float* out2 = out + (size_t)2 * MTOT * HNB;
    float* out3 = out + (size_t)3 * MTOT * HNB;

    const size_t carry_bytes = (size_t)NBLK * 256 * 4;          // 256 KB
    const size_t need = carry_bytes + BLOB_BYTES;               // ~0.9 MB
    float* carry; int cstride, do_fills; char* blobs;
    float *f1, *f3;
    if (ws_size >= need) {
        carry   = (float*)d_ws;
        cstride = 256;
        blobs   = (char*)d_ws + carry_bytes;
        f1 = out1; f3 = out3; do_fills = 0;
    } else {
        carry   = out3;                 // chunk's own out3 rows (blk*16384)
        cstride = CLK * HNB;            // 16384
        blobs   = (char*)out1;          // blobs live in out1 until k_apply fills
        f1 = nullptr; f3 = nullptr; do_fills = 1;
    }

    hipLaunchKernelGGL(k_prep, dim3(36), dim3(256), 0, stream, W1, W2, blobs);
    hipLaunchKernelGGL(k_mega, dim3(NBLK), dim3(512), 0, stream,
                       content, theta, b1, b2, logPi, logR, blobs,
                       out0, out2, f1, f3, carry, cstride);
    hipLaunchKernelGGL(k_cscan, dim3(NBAT), dim3(256), 0, stream,
                       logPi, logR, carry, cstride);
    hipLaunchKernelGGL(k_apply, dim3(NBLK), dim3(256), 0, stream,
                       logPi, logR, out0, out1, out3, carry, cstride, do_fills);
}